// Round 3
// baseline (145.398 us; speedup 1.0000x reference)
//
#include <hip/hip_runtime.h>
#include <hip/hip_bf16.h>
#include <math.h>

#define NPTS 65536
#define MRAY 16
#define BLOCK 512
#define PPW 4
#define PPB 32
#define GRID 2048

__device__ __forceinline__ float sigmoidf_(float x){ return 1.0f/(1.0f+__expf(-x)); }
__device__ __forceinline__ float wsum64(float x){
  x += __shfl_xor(x,1); x += __shfl_xor(x,2); x += __shfl_xor(x,4);
  x += __shfl_xor(x,8); x += __shfl_xor(x,16); x += __shfl_xor(x,32);
  return x;
}
__device__ __forceinline__ float sel4(float a, float b, float c, float d, int p){
  float lo = (p&1) ? b : a;
  float hi = (p&1) ? d : c;
  return (p&2) ? hi : lo;
}

// Classify ray_mask element dtype from the raw words.
// flag: 0 = 1-byte (uint8 bool), 1 = 4-byte word (int32/float32; !=0 decode), 2 = 8-byte (int64)
__global__ void detect_mask(const unsigned int* __restrict__ rm, int* __restrict__ flag) {
    bool bad = false, isf32 = false, odd_nz = false, even_one = false;
    for (int i = 0; i < 512; i++) {
        unsigned v = rm[i];
        if (v != 0u && v != 1u && v != 0x3F800000u) bad = true;
        if (v == 0x3F800000u) isf32 = true;
        if ((i & 1) && v != 0u) odd_nz = true;
        if (!(i & 1) && v != 0u) even_one = true;
    }
    int f;
    if (bad) f = 0;
    else if (isf32) f = 1;
    else if (!odd_nz && even_one) f = 2;
    else f = 1;
    flag[0] = f;
}

// LDS: wray[128][12] = per-col j: Wb1 rows {3,4,5, 9..14}[.,j] + Wb2[j][0..2]
//      baseu[32][129] = per-point base vector (first 192 floats of each wave slice double as nf staging)
// Wb1 const-part rows ({0,1,2,6,7,8,15..62,63}) and Wd1 are read straight from
// global: lane-indexed -> fully coalesced, L2-resident (~10 TB/s demand << 34.5 TB/s).
__global__ __launch_bounds__(BLOCK) void rb_main(
    const float* __restrict__ xyzs, const float* __restrict__ app,
    const float* __restrict__ vdirs, const float* __restrict__ normals,
    const float* __restrict__ noise, const float* __restrict__ uu,
    const float* __restrict__ Wd1, const float* __restrict__ bd1,
    const float* __restrict__ Wd2, const float* __restrict__ bd2,
    const float* __restrict__ Wb1, const float* __restrict__ bb1,
    const float* __restrict__ Wb2, const float* __restrict__ bb2,
    const void* __restrict__ raym, const int* __restrict__ flagp,
    float* __restrict__ out)
{
    __shared__ float wray_s[128*12];
    __shared__ float baseu[32*129];

    const int tid = threadIdx.x;
    for (int i = tid; i < 128*12; i += BLOCK){
        int j = i / 12, q = i - 12*j;
        float v;
        if (q < 9){ int row = q < 3 ? 3 + q : 6 + q; v = Wb1[row*128 + j]; }
        else       v = Wb2[j*3 + (q - 9)];
        wray_s[i] = v;
    }
    __syncthreads();  // only block-wide barrier; everything after is wave-local

    const int lane  = tid & 63;
    const int wid   = __builtin_amdgcn_readfirstlane(tid >> 6);
    const int pbase = blockIdx.x * PPB + wid * PPW;
    float* nfw = &baseu[wid * (PPW*129)];   // nf staging (overwritten later by base writes)

    // ---- phase 1: basis + local V (lanes 0..3) + noise-features ----
    float bs[12];
    #pragma unroll
    for (int i = 0; i < 12; i++) bs[i] = 0.f;
    if (lane < PPW){
        int n = pbase + lane;
        float nx = normals[n*3+0], ny = normals[n*3+1], nz = normals[n*3+2];
        float inv = 1.0f/(sqrtf(nx*nx+ny*ny+nz*nz)+1e-8f);
        float bx = nx*inv, by = ny*inv, bz = nz*inv;
        float ux, uy, uz;
        if (fabsf(bz) < 0.99f){ ux=0.f; uy=0.f; uz=1.f; } else { ux=1.f; uy=0.f; uz=0.f; }
        float tx = uy*bz-uz*by, ty = uz*bx-ux*bz, tz = ux*by-uy*bx;
        float tin = 1.0f/(sqrtf(tx*tx+ty*ty+tz*tz)+1e-8f);
        tx*=tin; ty*=tin; tz*=tin;
        float ex = by*tz-bz*ty, ey = bz*tx-bx*tz, ez = bx*ty-by*tx;
        bs[0]=tx; bs[1]=ex; bs[2]=bx; bs[3]=ty; bs[4]=ey; bs[5]=by; bs[6]=tz; bs[7]=ez; bs[8]=bz;
        // local-frame V = B^T * (-viewdir)
        float vx = vdirs[n*3+0], vy = vdirs[n*3+1], vz = vdirs[n*3+2];
        bs[9]  = -(tx*vx + ty*vy + tz*vz);
        bs[10] = -(ex*vx + ey*vy + ez*vz);
        bs[11] = -(bx*vx + by*vy + bz*vz);
    }
    #pragma unroll
    for (int c = 0; c < 3; c++){
        int idx = lane + 64*c;   // = p*48 + k, contiguous & coalesced
        nfw[idx] = fmaf(0.01f, noise[pbase*48 + idx], app[pbase*48 + idx]);
    }

    // ---- phase 2: dense layer1 + bounce const part (lane = hidden unit, 4 pts batched) ----
    float h[PPW][2], b[PPW][2];
    {
        float h0 = bd1[lane], h1 = bd1[lane+64];
        float b0 = bb1[lane], b1 = bb1[lane+64];
        #pragma unroll
        for (int p = 0; p < PPW; p++){ h[p][0]=h0; h[p][1]=h1; b[p][0]=b0; b[p][1]=b1; }
    }
    float vd[PPW][3];
    #pragma unroll
    for (int k = 0; k < 3; k++){
        float w0 = Wd1[k*128+lane], w1 = Wd1[k*128+64+lane];
        #pragma unroll
        for (int p = 0; p < PPW; p++){
            float s = xyzs[(pbase+p)*3+k];
            h[p][0]=fmaf(s,w0,h[p][0]); h[p][1]=fmaf(s,w1,h[p][1]);
        }
    }
    #pragma unroll
    for (int k = 0; k < 3; k++){
        float w0 = Wd1[(3+k)*128+lane], w1 = Wd1[(3+k)*128+64+lane];
        #pragma unroll
        for (int p = 0; p < PPW; p++){
            float s = vdirs[(pbase+p)*3+k]; vd[p][k] = s;
            h[p][0]=fmaf(s,w0,h[p][0]); h[p][1]=fmaf(s,w1,h[p][1]);
        }
    }
    #pragma unroll 8
    for (int k = 0; k < 48; k++){
        float w0 = Wd1[(6+k)*128+lane], w1 = Wd1[(6+k)*128+64+lane];
        #pragma unroll
        for (int p = 0; p < PPW; p++){
            float s = app[(pbase+p)*48+k];
            h[p][0]=fmaf(s,w0,h[p][0]); h[p][1]=fmaf(s,w1,h[p][1]);
        }
    }
    // bounce const: eV rows 0..2
    #pragma unroll
    for (int s = 0; s < 3; s++){
        float w0 = Wb1[s*128+lane], w1 = Wb1[s*128+64+lane];
        #pragma unroll
        for (int p = 0; p < PPW; p++){
            b[p][0]=fmaf(-vd[p][s],w0,b[p][0]); b[p][1]=fmaf(-vd[p][s],w1,b[p][1]);
        }
    }
    // eN rows 6..8
    #pragma unroll
    for (int s = 0; s < 3; s++){
        float w0 = Wb1[(6+s)*128+lane], w1 = Wb1[(6+s)*128+64+lane];
        #pragma unroll
        for (int p = 0; p < PPW; p++){
            float bn = __shfl(bs[3*s+2], p);
            b[p][0]=fmaf(bn,w0,b[p][0]); b[p][1]=fmaf(bn,w1,b[p][1]);
        }
    }
    // feat rows 15..62, nf from LDS broadcast
    #pragma unroll 4
    for (int k = 0; k < 48; k++){
        float w0 = Wb1[(15+k)*128+lane], w1 = Wb1[(15+k)*128+64+lane];
        #pragma unroll
        for (int p = 0; p < PPW; p++){
            float nfv = nfw[p*48+k];
            b[p][0]=fmaf(nfv,w0,b[p][0]); b[p][1]=fmaf(nfv,w1,b[p][1]);
        }
    }

    // dense layer2 (cols 0,1,2,6) + per-point scalars
    float wd2v[2][4];
    #pragma unroll
    for (int r = 0; r < 2; r++){
        int j = lane + 64*r;
        wd2v[r][0]=Wd2[j*9+0]; wd2v[r][1]=Wd2[j*9+1]; wd2v[r][2]=Wd2[j*9+2]; wd2v[r][3]=Wd2[j*9+6];
    }
    const float sbd2_0=bd2[0], sbd2_1=bd2[1], sbd2_2=bd2[2], sbd2_6=bd2[6];
    float dif[PPW][3], r1v[PPW], a2v[PPW], sclv[PPW];
    #pragma unroll
    for (int p = 0; p < PPW; p++){
        float hr0 = fmaxf(h[p][0],0.f), hr1 = fmaxf(h[p][1],0.f);
        float d0 = wsum64(fmaf(hr0,wd2v[0][0], hr1*wd2v[1][0])) + sbd2_0;
        float d1 = wsum64(fmaf(hr0,wd2v[0][1], hr1*wd2v[1][1])) + sbd2_1;
        float d2 = wsum64(fmaf(hr0,wd2v[0][2], hr1*wd2v[1][2])) + sbd2_2;
        float d6 = wsum64(fmaf(hr0,wd2v[0][3], hr1*wd2v[1][3])) + sbd2_6;
        dif[p][0]=sigmoidf_(d0); dif[p][1]=sigmoidf_(d1); dif[p][2]=sigmoidf_(d2);
        float r1 = sigmoidf_(d6)*0.98f + 0.01f;
        float a2 = r1*r1; a2 = a2*a2;
        r1v[p]=r1; a2v[p]=a2;
        sclv[p]=__expf(0.1f*__logf(fmaxf(a2,1e-6f)));
    }
    // ea1 row 63, then publish base (clobbers nf region -- all nf reads already done)
    {
        float w0 = Wb1[63*128+lane], w1 = Wb1[63*128+64+lane];
        #pragma unroll
        for (int p = 0; p < PPW; p++){
            float b0 = fmaf(r1v[p],w0,b[p][0]);
            float b1 = fmaf(r1v[p],w1,b[p][1]);
            baseu[(wid*PPW+p)*129 + lane]      = b0;
            baseu[(wid*PPW+p)*129 + 64 + lane] = b1;
        }
    }

    // ---- phase 3: rays (lane = pt*16 + ray), all in the local (TBN) frame ----
    const int p4 = lane >> 4;
    const int m  = lane & 15;
    const int n  = pbase + p4;
    float bas[9];
    #pragma unroll
    for (int i = 0; i < 9; i++) bas[i] = __shfl(bs[i], p4);
    float Vlx = __shfl(bs[9],  p4);
    float Vly = __shfl(bs[10], p4);
    float Vlz = __shfl(bs[11], p4);
    float a2s = sel4(a2v[0],a2v[1],a2v[2],a2v[3],p4);
    float scl = sel4(sclv[0],sclv[1],sclv[2],sclv[3],p4);

    float u1 = uu[(n*MRAY+m)*2+0];
    float u2 = uu[(n*MRAY+m)*2+1];
    float ct = sqrtf((1.0f-u1)/(1.0f+(a2s-1.0f)*u1));
    float st = sqrtf(fmaxf(1.0f-ct*ct,0.0f));
    float phi = 6.28318530717958647692f*u2;
    float hl0 = st*__cosf(phi), hl1 = st*__sinf(phi), hl2 = ct;
    // reflect in local frame: halfvec == Hl (orthonormal basis), diffvec == normalized local L
    float dvh = Vlx*hl0 + Vly*hl1 + Vlz*hl2;
    float t2 = dvh + dvh;
    float llx = fmaf(t2,hl0,-Vlx), lly = fmaf(t2,hl1,-Vly), llz = fmaf(t2,hl2,-Vlz);
    float linv = 1.0f/(sqrtf(llx*llx+lly*lly+llz*llz)+1e-8f);
    llx*=linv; lly*=linv; llz*=linv;
    // world L for incoming + first 3 bounce dims
    float rv0 = bas[0]*llx + bas[1]*lly + bas[2]*llz;
    float rv1 = bas[3]*llx + bas[4]*lly + bas[5]*llz;
    float rv2 = bas[6]*llx + bas[7]*lly + bas[8]*llz;
    float rv3 = hl0, rv4 = hl1, rv5 = hl2;
    float rv6 = llx, rv7 = lly, rv8 = llz;

    const float* bb = &baseu[(wid*PPW+p4)*129];
    float acc0=0.f, acc1=0.f, acc2=0.f;
    #pragma unroll 4
    for (int j = 0; j < 128; j++){
        const float4 wa  = *(const float4*)&wray_s[j*12];
        const float4 wbv = *(const float4*)&wray_s[j*12+4];
        const float4 wc  = *(const float4*)&wray_s[j*12+8];
        float hb = bb[j];
        hb = fmaf(rv0,wa.x,hb);  hb = fmaf(rv1,wa.y,hb);  hb = fmaf(rv2,wa.z,hb);
        hb = fmaf(rv3,wa.w,hb);  hb = fmaf(rv4,wbv.x,hb); hb = fmaf(rv5,wbv.y,hb);
        hb = fmaf(rv6,wbv.z,hb); hb = fmaf(rv7,wbv.w,hb); hb = fmaf(rv8,wc.x,hb);
        hb = fmaxf(hb,0.f);
        acc0 = fmaf(hb,wc.y,acc0); acc1 = fmaf(hb,wc.z,acc1); acc2 = fmaf(hb,wc.w,acc2);
    }

    const float sbb2_0=bb2[0], sbb2_1=bb2[1], sbb2_2=bb2[2];
    float e0 = sigmoidf_(acc0+sbb2_0), e1 = sigmoidf_(acc1+sbb2_1), e2 = sigmoidf_(acc2+sbb2_2);
    int midx = n*MRAY + m;
    const int flag = flagp[0];
    bool mk;
    if (flag == 0)      mk = ((const unsigned char*)raym)[midx] != 0;
    else if (flag == 2) mk = ((const unsigned long long*)raym)[midx] != 0ull;
    else                mk = ((const unsigned int*)raym)[midx] != 0u;
    float mf = mk ? 1.f : 0.f;
    float lzp = fmaxf(rv2, 0.f);
    float c0 = (lzp*1.0f+0.1f)*scl*e0*mf;
    float c1 = (lzp*0.9f+0.1f)*scl*e1*mf;
    float c2 = (lzp*0.8f+0.1f)*scl*e2*mf;
    #pragma unroll
    for (int off = 1; off < 16; off <<= 1){
        c0 += __shfl_xor(c0,off); c1 += __shfl_xor(c1,off);
        c2 += __shfl_xor(c2,off); mf += __shfl_xor(mf,off);
    }
    if (m == 0){
        float den = mf + 1e-8f;
        float d0 = sel4(dif[0][0],dif[1][0],dif[2][0],dif[3][0],p4);
        float d1 = sel4(dif[0][1],dif[1][1],dif[2][1],dif[3][1],p4);
        float d2 = sel4(dif[0][2],dif[1][2],dif[2][2],dif[3][2],p4);
        out[n*3+0] = c0/den + d0;
        out[n*3+1] = c1/den + d1;
        out[n*3+2] = c2/den + d2;
    }
}

extern "C" void kernel_launch(void* const* d_in, const int* in_sizes, int n_in,
                              void* d_out, int out_size, void* d_ws, size_t ws_size,
                              hipStream_t stream) {
    const float* xyzs    = (const float*)d_in[0];
    const float* app     = (const float*)d_in[1];
    const float* vdirs   = (const float*)d_in[2];
    const float* normals = (const float*)d_in[3];
    const float* noise   = (const float*)d_in[4];
    const float* uu      = (const float*)d_in[5];
    const float* Wd1     = (const float*)d_in[6];
    const float* bd1     = (const float*)d_in[7];
    const float* Wd2     = (const float*)d_in[8];
    const float* bd2     = (const float*)d_in[9];
    const float* Wb1     = (const float*)d_in[10];
    const float* bb1     = (const float*)d_in[11];
    const float* Wb2     = (const float*)d_in[12];
    const float* bb2     = (const float*)d_in[13];
    const void*  raym    = d_in[15];
    int* flag = (int*)d_ws;
    float* out = (float*)d_out;

    detect_mask<<<1, 1, 0, stream>>>((const unsigned int*)raym, flag);
    rb_main<<<GRID, BLOCK, 0, stream>>>(xyzs, app, vdirs, normals, noise, uu,
                                        Wd1, bd1, Wd2, bd2, Wb1, bb1, Wb2, bb2,
                                        raym, flag, out);
}

// Round 4
// 126.465 us; speedup vs baseline: 1.1497x; 1.1497x over previous
//
#include <hip/hip_runtime.h>
#include <hip/hip_bf16.h>
#include <math.h>

#define NPTS 65536
#define MRAY 16
#define BLOCK 256
#define PPW 4
#define PPB 16
#define GRID 4096

typedef float f2 __attribute__((ext_vector_type(2)));

__device__ __forceinline__ f2 fma2(f2 a, f2 b, f2 c){
#if __has_builtin(__builtin_elementwise_fma)
    return __builtin_elementwise_fma(a, b, c);
#else
    f2 r; r.x = fmaf(a.x, b.x, c.x); r.y = fmaf(a.y, b.y, c.y); return r;
#endif
}
__device__ __forceinline__ f2 max2z(f2 a){
#if __has_builtin(__builtin_elementwise_max)
    f2 z = {0.f, 0.f};
    return __builtin_elementwise_max(a, z);
#else
    f2 r; r.x = fmaxf(a.x, 0.f); r.y = fmaxf(a.y, 0.f); return r;
#endif
}
__device__ __forceinline__ float sigmoidf_(float x){ return 1.0f/(1.0f+__expf(-x)); }
__device__ __forceinline__ float wsum64(float x){
  x += __shfl_xor(x,1); x += __shfl_xor(x,2); x += __shfl_xor(x,4);
  x += __shfl_xor(x,8); x += __shfl_xor(x,16); x += __shfl_xor(x,32);
  return x;
}
__device__ __forceinline__ float sel4(float a, float b, float c, float d, int p){
  float lo = (p&1) ? b : a;
  float hi = (p&1) ? d : c;
  return (p&2) ? hi : lo;
}

// prep: classify ray_mask dtype (ws[0] as int) + repack Wb2^T [3][128] at ws+4 floats.
// flag: 0 = 1-byte (uint8 bool), 1 = 4-byte word (int32/float32; !=0 decode), 2 = 8-byte (int64)
__global__ void prep(const unsigned int* __restrict__ rm, const float* __restrict__ Wb2,
                     float* __restrict__ ws) {
    int t = threadIdx.x;
    if (t < 128){
        ws[4 + 0*128 + t] = Wb2[t*3+0];
        ws[4 + 1*128 + t] = Wb2[t*3+1];
        ws[4 + 2*128 + t] = Wb2[t*3+2];
    }
    if (t == 0){
        bool bad = false, isf32 = false, odd_nz = false, even_one = false;
        for (int i = 0; i < 512; i++) {
            unsigned v = rm[i];
            if (v != 0u && v != 1u && v != 0x3F800000u) bad = true;
            if (v == 0x3F800000u) isf32 = true;
            if ((i & 1) && v != 0u) odd_nz = true;
            if (!(i & 1) && v != 0u) even_one = true;
        }
        int f;
        if (bad) f = 0;
        else if (isf32) f = 1;
        else if (!odd_nz && even_one) f = 2;
        else f = 1;
        ((int*)ws)[0] = f;
    }
}

// Wave-autonomous: no __syncthreads anywhere. LDS only for per-wave nf staging /
// base vectors (baseu, stride 132 for 16B alignment). All weights read from
// global: lane-indexed (coalesced VMEM, L1/L2-hit) in phase 2, wave-uniform
// s_load in phase 3.
__global__ __launch_bounds__(BLOCK, 4) void rb_main(
    const float* __restrict__ xyzs, const float* __restrict__ app,
    const float* __restrict__ vdirs, const float* __restrict__ normals,
    const float* __restrict__ noise, const float* __restrict__ uu,
    const float* __restrict__ Wd1, const float* __restrict__ bd1,
    const float* __restrict__ Wd2, const float* __restrict__ bd2,
    const float* __restrict__ Wb1, const float* __restrict__ bb1,
    const float* __restrict__ Wb2, const float* __restrict__ bb2,
    const void* __restrict__ raym, const float* __restrict__ wsf,
    float* __restrict__ out)
{
    __shared__ float baseu[PPB*132];     // 16 pts x 132 (8448 B)

    const int tid  = threadIdx.x;
    const int lane = tid & 63;
    const int wid  = __builtin_amdgcn_readfirstlane(tid >> 6);
    const int pbase = blockIdx.x * PPB + wid * PPW;
    float* nfw = &baseu[wid * (PPW*132)];   // nf staging [48][4] (192 floats; clobbered later by base)

    const int flag = ((const int*)wsf)[0];
    const float* wb2t = wsf + 4;            // [3][128]

    // ---- phase 1: basis + local V (lanes 0..3) + noise-features ----
    float bs[12];
    #pragma unroll
    for (int i = 0; i < 12; i++) bs[i] = 0.f;
    if (lane < PPW){
        int n = pbase + lane;
        float nx = normals[n*3+0], ny = normals[n*3+1], nz = normals[n*3+2];
        float inv = 1.0f/(sqrtf(nx*nx+ny*ny+nz*nz)+1e-8f);
        float bx = nx*inv, by = ny*inv, bz = nz*inv;
        float ux, uy, uz;
        if (fabsf(bz) < 0.99f){ ux=0.f; uy=0.f; uz=1.f; } else { ux=1.f; uy=0.f; uz=0.f; }
        float tx = uy*bz-uz*by, ty = uz*bx-ux*bz, tz = ux*by-uy*bx;
        float tin = 1.0f/(sqrtf(tx*tx+ty*ty+tz*tz)+1e-8f);
        tx*=tin; ty*=tin; tz*=tin;
        float ex = by*tz-bz*ty, ey = bz*tx-bx*tz, ez = bx*ty-by*tx;
        bs[0]=tx; bs[1]=ex; bs[2]=bx; bs[3]=ty; bs[4]=ey; bs[5]=by; bs[6]=tz; bs[7]=ez; bs[8]=bz;
        float vx = vdirs[n*3+0], vy = vdirs[n*3+1], vz = vdirs[n*3+2];
        bs[9]  = -(tx*vx + ty*vy + tz*vz);
        bs[10] = -(ex*vx + ey*vy + ez*vz);
        bs[11] = -(bx*vx + by*vy + bz*vz);
    }
    #pragma unroll
    for (int c = 0; c < 3; c++){
        int idx = lane + 64*c;   // = p*48 + k over 4 pts
        float v = fmaf(0.01f, noise[pbase*48 + idx], app[pbase*48 + idx]);
        int p = idx / 48, k = idx - 48*p;
        nfw[k*4 + p] = v;        // [48][4] layout for f2 pair reads
    }

    // ---- phase 2: dense layer1 + bounce const part (lane = hidden unit, 4 pts as 2 f2-pairs) ----
    f2 h2[2][2], b2[2][2];   // [pair][half]
    {
        float h0 = bd1[lane], h1 = bd1[lane+64];
        float c0 = bb1[lane], c1 = bb1[lane+64];
        #pragma unroll
        for (int q = 0; q < 2; q++){
            h2[q][0] = f2{h0,h0}; h2[q][1] = f2{h1,h1};
            b2[q][0] = f2{c0,c0}; b2[q][1] = f2{c1,c1};
        }
    }
    float vd[PPW][3];
    #pragma unroll
    for (int k = 0; k < 3; k++){
        float w0 = Wd1[k*128+lane], w1 = Wd1[k*128+64+lane];
        f2 sA = { xyzs[(pbase+0)*3+k], xyzs[(pbase+1)*3+k] };
        f2 sB = { xyzs[(pbase+2)*3+k], xyzs[(pbase+3)*3+k] };
        h2[0][0]=fma2(sA,f2{w0,w0},h2[0][0]); h2[0][1]=fma2(sA,f2{w1,w1},h2[0][1]);
        h2[1][0]=fma2(sB,f2{w0,w0},h2[1][0]); h2[1][1]=fma2(sB,f2{w1,w1},h2[1][1]);
    }
    #pragma unroll
    for (int k = 0; k < 3; k++){
        float w0 = Wd1[(3+k)*128+lane], w1 = Wd1[(3+k)*128+64+lane];
        #pragma unroll
        for (int p = 0; p < PPW; p++) vd[p][k] = vdirs[(pbase+p)*3+k];
        f2 sA = { vd[0][k], vd[1][k] };
        f2 sB = { vd[2][k], vd[3][k] };
        h2[0][0]=fma2(sA,f2{w0,w0},h2[0][0]); h2[0][1]=fma2(sA,f2{w1,w1},h2[0][1]);
        h2[1][0]=fma2(sB,f2{w0,w0},h2[1][0]); h2[1][1]=fma2(sB,f2{w1,w1},h2[1][1]);
    }
    #pragma unroll 8
    for (int k = 0; k < 48; k++){
        float w0 = Wd1[(6+k)*128+lane], w1 = Wd1[(6+k)*128+64+lane];
        f2 sA = { app[(pbase+0)*48+k], app[(pbase+1)*48+k] };
        f2 sB = { app[(pbase+2)*48+k], app[(pbase+3)*48+k] };
        h2[0][0]=fma2(sA,f2{w0,w0},h2[0][0]); h2[0][1]=fma2(sA,f2{w1,w1},h2[0][1]);
        h2[1][0]=fma2(sB,f2{w0,w0},h2[1][0]); h2[1][1]=fma2(sB,f2{w1,w1},h2[1][1]);
    }
    // bounce const: eV rows 0..2 (-viewdir)
    #pragma unroll
    for (int s = 0; s < 3; s++){
        float w0 = Wb1[s*128+lane], w1 = Wb1[s*128+64+lane];
        f2 sA = { -vd[0][s], -vd[1][s] };
        f2 sB = { -vd[2][s], -vd[3][s] };
        b2[0][0]=fma2(sA,f2{w0,w0},b2[0][0]); b2[0][1]=fma2(sA,f2{w1,w1},b2[0][1]);
        b2[1][0]=fma2(sB,f2{w0,w0},b2[1][0]); b2[1][1]=fma2(sB,f2{w1,w1},b2[1][1]);
    }
    // eN rows 6..8
    #pragma unroll
    for (int s = 0; s < 3; s++){
        float w0 = Wb1[(6+s)*128+lane], w1 = Wb1[(6+s)*128+64+lane];
        float bn0 = __shfl(bs[3*s+2], 0), bn1 = __shfl(bs[3*s+2], 1);
        float bn2 = __shfl(bs[3*s+2], 2), bn3 = __shfl(bs[3*s+2], 3);
        f2 sA = { bn0, bn1 }, sB = { bn2, bn3 };
        b2[0][0]=fma2(sA,f2{w0,w0},b2[0][0]); b2[0][1]=fma2(sA,f2{w1,w1},b2[0][1]);
        b2[1][0]=fma2(sB,f2{w0,w0},b2[1][0]); b2[1][1]=fma2(sB,f2{w1,w1},b2[1][1]);
    }
    // feat rows 15..62 (nf pairs from LDS [48][4])
    const f2* nfp = (const f2*)nfw;
    #pragma unroll 8
    for (int k = 0; k < 48; k++){
        float w0 = Wb1[(15+k)*128+lane], w1 = Wb1[(15+k)*128+64+lane];
        f2 nA = nfp[k*2+0], nB = nfp[k*2+1];
        b2[0][0]=fma2(nA,f2{w0,w0},b2[0][0]); b2[0][1]=fma2(nA,f2{w1,w1},b2[0][1]);
        b2[1][0]=fma2(nB,f2{w0,w0},b2[1][0]); b2[1][1]=fma2(nB,f2{w1,w1},b2[1][1]);
    }

    // dense layer2 (cols 0,1,2,6)
    float wd2v[2][4];
    #pragma unroll
    for (int r = 0; r < 2; r++){
        int j = lane + 64*r;
        wd2v[r][0]=Wd2[j*9+0]; wd2v[r][1]=Wd2[j*9+1]; wd2v[r][2]=Wd2[j*9+2]; wd2v[r][3]=Wd2[j*9+6];
    }
    const float sbd2_0=bd2[0], sbd2_1=bd2[1], sbd2_2=bd2[2], sbd2_6=bd2[6];
    float hr[PPW][2];
    hr[0][0]=fmaxf(h2[0][0].x,0.f); hr[0][1]=fmaxf(h2[0][1].x,0.f);
    hr[1][0]=fmaxf(h2[0][0].y,0.f); hr[1][1]=fmaxf(h2[0][1].y,0.f);
    hr[2][0]=fmaxf(h2[1][0].x,0.f); hr[2][1]=fmaxf(h2[1][1].x,0.f);
    hr[3][0]=fmaxf(h2[1][0].y,0.f); hr[3][1]=fmaxf(h2[1][1].y,0.f);
    float dif[PPW][3], r1v[PPW], a2v[PPW], sclv[PPW];
    #pragma unroll
    for (int p = 0; p < PPW; p++){
        float d0 = wsum64(fmaf(hr[p][0],wd2v[0][0], hr[p][1]*wd2v[1][0])) + sbd2_0;
        float d1 = wsum64(fmaf(hr[p][0],wd2v[0][1], hr[p][1]*wd2v[1][1])) + sbd2_1;
        float d2 = wsum64(fmaf(hr[p][0],wd2v[0][2], hr[p][1]*wd2v[1][2])) + sbd2_2;
        float d6 = wsum64(fmaf(hr[p][0],wd2v[0][3], hr[p][1]*wd2v[1][3])) + sbd2_6;
        dif[p][0]=sigmoidf_(d0); dif[p][1]=sigmoidf_(d1); dif[p][2]=sigmoidf_(d2);
        float r1 = sigmoidf_(d6)*0.98f + 0.01f;
        float a2 = r1*r1; a2 = a2*a2;
        r1v[p]=r1; a2v[p]=a2;
        sclv[p]=__expf(0.1f*__logf(fmaxf(a2,1e-6f)));
    }
    // ea1 row 63, publish base (stride 132; clobbers nf region -- all nf reads done)
    {
        float w0 = Wb1[63*128+lane], w1 = Wb1[63*128+64+lane];
        float bl[PPW][2];
        bl[0][0]=b2[0][0].x; bl[0][1]=b2[0][1].x;
        bl[1][0]=b2[0][0].y; bl[1][1]=b2[0][1].y;
        bl[2][0]=b2[1][0].x; bl[2][1]=b2[1][1].x;
        bl[3][0]=b2[1][0].y; bl[3][1]=b2[1][1].y;
        #pragma unroll
        for (int p = 0; p < PPW; p++){
            baseu[(wid*PPW+p)*132 + lane]      = fmaf(r1v[p], w0, bl[p][0]);
            baseu[(wid*PPW+p)*132 + 64 + lane] = fmaf(r1v[p], w1, bl[p][1]);
        }
    }

    // ---- phase 3: rays (lane = pt*16 + ray), local (TBN) frame ----
    const int p4 = lane >> 4;
    const int m  = lane & 15;
    const int n  = pbase + p4;
    float bas[9];
    #pragma unroll
    for (int i = 0; i < 9; i++) bas[i] = __shfl(bs[i], p4);
    float Vlx = __shfl(bs[9],  p4);
    float Vly = __shfl(bs[10], p4);
    float Vlz = __shfl(bs[11], p4);
    float a2s = sel4(a2v[0],a2v[1],a2v[2],a2v[3],p4);
    float scl = sel4(sclv[0],sclv[1],sclv[2],sclv[3],p4);

    float u1 = uu[(n*MRAY+m)*2+0];
    float u2 = uu[(n*MRAY+m)*2+1];
    float ct = sqrtf((1.0f-u1)/(1.0f+(a2s-1.0f)*u1));
    float st = sqrtf(fmaxf(1.0f-ct*ct,0.0f));
    float phi = 6.28318530717958647692f*u2;
    float hl0 = st*__cosf(phi), hl1 = st*__sinf(phi), hl2 = ct;
    float dvh = Vlx*hl0 + Vly*hl1 + Vlz*hl2;
    float t2 = dvh + dvh;
    float llx = fmaf(t2,hl0,-Vlx), lly = fmaf(t2,hl1,-Vly), llz = fmaf(t2,hl2,-Vlz);
    float linv = 1.0f/(sqrtf(llx*llx+lly*lly+llz*llz)+1e-8f);
    llx*=linv; lly*=linv; llz*=linv;
    float rv[9];
    rv[0] = bas[0]*llx + bas[1]*lly + bas[2]*llz;   // world L
    rv[1] = bas[3]*llx + bas[4]*lly + bas[5]*llz;
    rv[2] = bas[6]*llx + bas[7]*lly + bas[8]*llz;
    rv[3] = hl0; rv[4] = hl1; rv[5] = hl2;          // halfvec (local)
    rv[6] = llx; rv[7] = lly; rv[8] = llz;          // diffvec (local)

    // Wb1 ray rows {3,4,5,9,10,11,12,13,14} * 128 (byte offsets folded at compile time)
    const int ROWOFF[9] = {3*128, 4*128, 5*128, 9*128, 10*128, 11*128, 12*128, 13*128, 14*128};

    const float* bb = &baseu[(wid*PPW+p4)*132];
    f2 acc[3] = { f2{0.f,0.f}, f2{0.f,0.f}, f2{0.f,0.f} };
    #pragma unroll 2
    for (int jb = 0; jb < 128; jb += 4){
        const int jo = __builtin_amdgcn_readfirstlane(jb);
        const float4 b4 = *(const float4*)(bb + jo);
        f2 hb01 = { b4.x, b4.y };
        f2 hb23 = { b4.z, b4.w };
        #pragma unroll
        for (int k = 0; k < 9; k++){
            const float* wr = Wb1 + ROWOFF[k] + jo;     // uniform -> s_load_dwordx4
            f2 w01 = { wr[0], wr[1] };
            f2 w23 = { wr[2], wr[3] };
            f2 rvk = { rv[k], rv[k] };
            hb01 = fma2(rvk, w01, hb01);
            hb23 = fma2(rvk, w23, hb23);
        }
        hb01 = max2z(hb01);
        hb23 = max2z(hb23);
        #pragma unroll
        for (int cc = 0; cc < 3; cc++){
            const float* wr = wb2t + cc*128 + jo;       // uniform -> s_load_dwordx4
            f2 w01 = { wr[0], wr[1] };
            f2 w23 = { wr[2], wr[3] };
            acc[cc] = fma2(hb01, w01, acc[cc]);
            acc[cc] = fma2(hb23, w23, acc[cc]);
        }
    }

    float e0 = sigmoidf_(acc[0].x + acc[0].y + bb2[0]);
    float e1 = sigmoidf_(acc[1].x + acc[1].y + bb2[1]);
    float e2 = sigmoidf_(acc[2].x + acc[2].y + bb2[2]);
    int midx = n*MRAY + m;
    bool mk;
    if (flag == 0)      mk = ((const unsigned char*)raym)[midx] != 0;
    else if (flag == 2) mk = ((const unsigned long long*)raym)[midx] != 0ull;
    else                mk = ((const unsigned int*)raym)[midx] != 0u;
    float mf = mk ? 1.f : 0.f;
    float lzp = fmaxf(rv[2], 0.f);
    float c0 = (lzp*1.0f+0.1f)*scl*e0*mf;
    float c1 = (lzp*0.9f+0.1f)*scl*e1*mf;
    float c2 = (lzp*0.8f+0.1f)*scl*e2*mf;
    #pragma unroll
    for (int off = 1; off < 16; off <<= 1){
        c0 += __shfl_xor(c0,off); c1 += __shfl_xor(c1,off);
        c2 += __shfl_xor(c2,off); mf += __shfl_xor(mf,off);
    }
    if (m == 0){
        float den = mf + 1e-8f;
        float d0 = sel4(dif[0][0],dif[1][0],dif[2][0],dif[3][0],p4);
        float d1 = sel4(dif[0][1],dif[1][1],dif[2][1],dif[3][1],p4);
        float d2 = sel4(dif[0][2],dif[1][2],dif[2][2],dif[3][2],p4);
        out[n*3+0] = c0/den + d0;
        out[n*3+1] = c1/den + d1;
        out[n*3+2] = c2/den + d2;
    }
}

extern "C" void kernel_launch(void* const* d_in, const int* in_sizes, int n_in,
                              void* d_out, int out_size, void* d_ws, size_t ws_size,
                              hipStream_t stream) {
    const float* xyzs    = (const float*)d_in[0];
    const float* app     = (const float*)d_in[1];
    const float* vdirs   = (const float*)d_in[2];
    const float* normals = (const float*)d_in[3];
    const float* noise   = (const float*)d_in[4];
    const float* uu      = (const float*)d_in[5];
    const float* Wd1     = (const float*)d_in[6];
    const float* bd1     = (const float*)d_in[7];
    const float* Wd2     = (const float*)d_in[8];
    const float* bd2     = (const float*)d_in[9];
    const float* Wb1     = (const float*)d_in[10];
    const float* bb1     = (const float*)d_in[11];
    const float* Wb2     = (const float*)d_in[12];
    const float* bb2     = (const float*)d_in[13];
    const void*  raym    = d_in[15];
    float* wsf = (float*)d_ws;
    float* out = (float*)d_out;

    prep<<<1, 128, 0, stream>>>((const unsigned int*)raym, Wb2, wsf);
    rb_main<<<GRID, BLOCK, 0, stream>>>(xyzs, app, vdirs, normals, noise, uu,
                                        Wd1, bd1, Wd2, bd2, Wb1, bb1, Wb2, bb2,
                                        raym, wsf, out);
}